// Round 8
// baseline (214.275 us; speedup 1.0000x reference)
//
#include <hip/hip_runtime.h>

typedef float v2f __attribute__((ext_vector_type(2)));

// ---------------- problem constants ----------------
#define B_    4
#define C_    4
#define Q_    8
#define J_    5
#define T_    15
#define NSIG  65536
#define N2SIG 32768
#define NOUT  16384

// ---------------- wavelet filters ----------------
constexpr float H0Oc[13] = {
    -0.00455690456024f, -0.00543947593727f,  0.01702522388155f,  0.02382538479492f,
    -0.10671180468666f,  0.01186609203379f,  0.56881042071212f,  0.75614564389252f,
     0.27529538466888f, -0.11720388769911f, -0.03887280126882f,  0.03466034684485f,
    -0.00388321199915f };
constexpr float H1Oc[13] = {
    -0.00388321199915f, -0.03466034684485f, -0.03887280126882f,  0.11720388769911f,
     0.27529538466888f, -0.75614564389252f,  0.56881042071212f, -0.01186609203379f,
    -0.10671180468666f, -0.02382538479492f,  0.01702522388155f,  0.00543947593727f,
    -0.00455690456024f };
constexpr float H0Ac[10] = {
     0.03516384f, 0.0f, -0.08832942f, 0.23389032f, 0.76027237f,
     0.58751830f, 0.0f, -0.11430184f, 0.0f, 0.0f };
constexpr float H0Bc[10] = {
     0.0f, 0.0f, -0.11430184f, 0.0f, 0.58751830f,
     0.76027237f, 0.23389032f, -0.08832942f, 0.0f, 0.03516384f };
constexpr float H1Ac[10] = {
     0.0f, 0.0f, -0.11430184f, 0.0f, 0.58751830f,
    -0.76027237f, 0.23389032f, 0.08832942f, 0.0f, -0.03516384f };
constexpr float H1Bc[10] = {
    -0.03516384f, 0.0f, 0.08832942f, 0.23389032f, -0.76027237f,
     0.58751830f, 0.0f, -0.11430184f, 0.0f, 0.0f };

// fused two-stage lowpass+decimate: out[m] = sum_n g[n] * u[4m + n - 18]
struct Gtab { float v[37]; };
constexpr Gtab make_g() {
    Gtab g{};
    for (int n = 0; n < 37; ++n) {
        float s = 0.f;
        for (int k = 0; k < 13; ++k) {
            int l = n - 2 * k;
            if (l >= 0 && l < 13) s += H0Oc[k] * H0Oc[l];
        }
        g.v[n] = s;
    }
    return g;
}
constexpr Gtab cG = make_g();

// ---------------- tiling ----------------
#define M2    256                // final outputs per tile
#define NUcnt 1057               // 4*(M2-1) + 37
#define NBcnt 1169               // bp samples needed
#define S_    1320               // x window (halo 73 left / 74 right)

// LDS carve (floats):
//   PA  v2f[1320]  @ 0      (X scalar[1320] aliases start; dead before lv1 write)
//   PB  v2f[1320]  @ 2640   (L1 scalar[1320] aliases start; dead before lv2 write)
//   sRI v2f[1200]  @ 5280
//   U   uint2[1064]@ 7680   (4 bf16 q's per sample)
#define SMEM_FLOATS 9808       // 39232 B -> 4 blocks/CU

__device__ __forceinline__ v2f zmask(v2f a, bool ok) {
    if (!ok) { a.x = 0.f; a.y = 0.f; }
    return a;
}
__device__ __forceinline__ unsigned pack2bf(float a, float b) {
    unsigned ua = __float_as_uint(a) + 0x8000u;
    unsigned ub = __float_as_uint(b) + 0x8000u;
    return (ua >> 16) | (ub & 0xffff0000u);
}
__device__ __forceinline__ float unpk_lo(unsigned x) { return __uint_as_float(x << 16); }
__device__ __forceinline__ float unpk_hi(unsigned x) { return __uint_as_float(x & 0xffff0000u); }

// ---------------- u pass: 4 q's, 15 fp32 v2f taps (R5 shape), bf16x4 out ----
template<int D, int JJ>
__device__ __forceinline__ void u_pass(
        int g2, const v2f* __restrict__ sRI, uint2* __restrict__ U,
        const float* __restrict__ cw, const float* __restrict__ roots,
        float beta, int c, int m0, int tid) {
    const float lg_is = -0.5f * (float)JJ;
    const float beta2 = beta * exp2f(0.5f * (float)JJ);
    const int   u_lo  = 4 * m0 - 18;
    float w[4][T_], al[4], cq[4];
    #pragma unroll
    for (int qq = 0; qq < 4; ++qq) {
        const int o = c * Q_ + g2 * 4 + qq;
        #pragma unroll
        for (int t = 0; t < T_; t++) w[qq][t] = cw[(size_t)(JJ * 32 + o) * T_ + t];
        al[qq] = 1.f / (1.f + __expf(-roots[JJ * 32 + o]));
        cq[qq] = al[qq] * lg_is;
    }
    for (int i = tid; i < NUcnt; i += 256) {
        const int n = u_lo + i;
        const bool ok = ((unsigned)n < (unsigned)NSIG);
        const v2f* tp = sRI + (i + 56 - 7 * D);
        v2f tap[T_];
        #pragma unroll
        for (int t = 0; t < T_; t++) tap[t] = tp[t * D];
        float uq[4];
        #pragma unroll
        for (int qq = 0; qq < 4; ++qq) {
            v2f ri; ri.x = 0.f; ri.y = 0.f;
            #pragma unroll
            for (int t = 0; t < T_; t++) ri += w[qq][t] * tap[t];
            float z2 = fmaf(ri.x, ri.x, ri.y * ri.y);
            float us = sqrtf(z2);
            float lg = __log2f(us + beta2);
            float u  = exp2f(fmaf(al[qq], lg, cq[qq]));
            uq[qq] = ok ? u : 0.f;
        }
        uint2 p;
        p.x = pack2bf(uq[0], uq[1]);
        p.y = pack2bf(uq[2], uq[3]);
        U[i] = p;
    }
}

// ---------------- ds pass: fused 37-tap stride-4 downsample on bf16x4 ----
template<int JJ>
__device__ __forceinline__ void ds_pass(
        int g2, const uint2* __restrict__ U,
        int b, int c, int m0, int mt, int tid, float* __restrict__ out) {
    const int m = m0 + tid;
    const bool edge = (mt == 0 && tid < 3) || (mt == 63 && tid >= 253);
    float a0 = 0.f, a1 = 0.f, a2 = 0.f, a3 = 0.f;
    #pragma unroll
    for (int nn = 0; nn < 37; ++nn) {
        uint2 t = U[4 * tid + nn];
        a0 = fmaf(cG.v[nn], unpk_lo(t.x), a0);
        a1 = fmaf(cG.v[nn], unpk_hi(t.x), a1);
        a2 = fmaf(cG.v[nn], unpk_lo(t.y), a2);
        a3 = fmaf(cG.v[nn], unpk_hi(t.y), a3);
    }
    if (edge) {
        float e0 = 0.f, e1 = 0.f, e2 = 0.f, e3 = 0.f;
        for (int k = 0; k < 13; ++k) {
            int p = 2 * m + k - 6;
            if (p < 0 || p >= N2SIG) continue;
            float v0 = 0.f, v1 = 0.f, v2 = 0.f, v3 = 0.f;
            for (int l = 0; l < 13; ++l) {
                uint2 t = U[4 * tid + 2 * k + l];
                v0 = fmaf(H0Oc[l], unpk_lo(t.x), v0);
                v1 = fmaf(H0Oc[l], unpk_hi(t.x), v1);
                v2 = fmaf(H0Oc[l], unpk_lo(t.y), v2);
                v3 = fmaf(H0Oc[l], unpk_hi(t.y), v3);
            }
            e0 = fmaf(H0Oc[k], v0, e0); e1 = fmaf(H0Oc[k], v1, e1);
            e2 = fmaf(H0Oc[k], v2, e2); e3 = fmaf(H0Oc[k], v3, e3);
        }
        a0 = e0; a1 = e1; a2 = e2; a3 = e3;
    }
    const int o = c * Q_ + g2 * 4;
    float* ob = out + ((size_t)b * 160 + JJ * 32 + o) * NOUT + m;
    ob[0]        = a0;
    ob[NOUT]     = a1;
    ob[2 * NOUT] = a2;
    ob[3 * NOUT] = a3;
}

// ---------------- chain helpers (lane-stride-1, R5-verified indices) ----
// 10-tap pair conv from scalar source
__device__ __forceinline__ void conv10s(
        const float* __restrict__ src, v2f* __restrict__ dst, int dstShift,
        const float (&hA)[10], const float (&hB)[10],
        int plo, int phi, int ofs, int tid) {
    for (int p = plo + tid; p < phi; p += 256) {
        v2f a; a.x = 0.f; a.y = 0.f;
        #pragma unroll
        for (int k = 0; k < 10; k++) {
            v2f hk; hk.x = hA[k]; hk.y = hB[k];
            a += hk * src[p + k - 4];
        }
        dst[p - dstShift] = zmask(a, (unsigned)(ofs + p) < (unsigned)NSIG);
    }
}
// 10-tap pair conv from v2f source, dilation d (runtime small const)
template<int DD>
__device__ __forceinline__ void conv10v(
        const v2f* __restrict__ src, v2f* __restrict__ dst, int dstShift,
        const float (&hA)[10], const float (&hB)[10], int pad,
        int plo, int phi, int ofs, int tid) {
    for (int p = plo + tid; p < phi; p += 256) {
        v2f a; a.x = 0.f; a.y = 0.f;
        #pragma unroll
        for (int k = 0; k < 10; k++) {
            v2f hk; hk.x = hA[k]; hk.y = hB[k];
            a += hk * src[p + k * DD - pad];
        }
        dst[p - dstShift] = zmask(a, (unsigned)(ofs + p) < (unsigned)NSIG);
    }
}

// ---------------- fused kernel: one block per (ch, tile), all j's ----------
__global__ __launch_bounds__(256, 4) void murenn_all(
        const float* __restrict__ x,
        const float* __restrict__ cw,
        const float* __restrict__ roots,
        const float* __restrict__ beta_p,
        float* __restrict__ out) {
    __shared__ __align__(16) float smem[SMEM_FLOATS];
    float* X   = smem;                       // scalar alias of PA
    v2f*   PA  = (v2f*)smem;
    float* L1  = smem + 2640;                // scalar alias of PB
    v2f*   PB  = (v2f*)(smem + 2640);
    v2f*   sRI = (v2f*)(smem + 5280);        // 1200 v2f
    uint2* U   = (uint2*)(smem + 7680);      // 1064 uint2

    const int tid = threadIdx.x;
    const int mt  = blockIdx.x;              // 0..63
    const int ch  = blockIdx.y;              // b*C + c
    const int b   = ch >> 2, c = ch & 3;
    const int m0  = mt * M2;
    const int ofs = 4 * m0 - 147;            // bp index 0 at window p = 73
    const float beta = beta_p[0];
    const float* xc = x + (size_t)ch * NSIG;

    // ---- phase 1: load x window into X ----
    for (int p = tid; p < S_; p += 256) {
        int g = ofs + p;
        X[p] = ((unsigned)g < (unsigned)NSIG) ? xc[g] : 0.f;
    }
    __syncthreads();

    // ---- phase 2: L1 = conv13(X,H0O);  bp0 = conv13(X,H1O) -> sRI ----
    for (int p = 6 + tid; p < 1313; p += 256) {
        float a = 0.f;
        #pragma unroll
        for (int k = 0; k < 13; k++) a = fmaf(H0Oc[k], X[p + k - 6], a);
        L1[p] = ((unsigned)(ofs + p) < (unsigned)NSIG) ? a : 0.f;
    }
    for (int i = tid; i < NBcnt; i += 256) {
        int p = 73 + i;
        float a = 0.f;
        #pragma unroll
        for (int k = 0; k < 13; k++) a = fmaf(H1Oc[k], X[p + k - 6], a);
        if ((unsigned)(ofs + p) >= (unsigned)NSIG) a = 0.f;
        v2f r; r.x = a; r.y = a;
        sRI[i] = r;
    }
    __syncthreads();

    // ================= j = 0 (D=1), interleave lv1 / bp1 =================
    u_pass<1, 0>(0, sRI, U, cw, roots, beta, c, m0, tid);
    __syncthreads();
    ds_pass<0>(0, U, b, c, m0, mt, tid, out);
    conv10s(L1, PA, 0, H0Ac, H0Bc, 10, 1308, ofs, tid);          // lv1 lowpass (X dead)
    __syncthreads();
    u_pass<1, 0>(1, sRI, U, cw, roots, beta, c, m0, tid);
    __syncthreads();
    ds_pass<0>(1, U, b, c, m0, mt, tid, out);
    conv10s(L1, sRI, 73, H1Ac, H1Bc, 73, 73 + NBcnt, ofs, tid);  // bp1 -> sRI
    __syncthreads();

    // ================= j = 1 (D=1), interleave lv2 / bp2 =================
    u_pass<1, 1>(0, sRI, U, cw, roots, beta, c, m0, tid);
    __syncthreads();
    ds_pass<1>(0, U, b, c, m0, mt, tid, out);
    conv10v<2>(PA, PB, 0, H0Ac, H0Bc, 9, 19, 1299, ofs, tid);    // lv2 lowpass (L1 dead)
    __syncthreads();
    u_pass<1, 1>(1, sRI, U, cw, roots, beta, c, m0, tid);
    __syncthreads();
    ds_pass<1>(1, U, b, c, m0, mt, tid, out);
    conv10v<2>(PA, sRI, 73, H1Ac, H1Bc, 9, 73, 73 + NBcnt, ofs, tid);  // bp2
    __syncthreads();

    // ================= j = 2 (D=2), interleave lv3 / bp3 =================
    u_pass<2, 2>(0, sRI, U, cw, roots, beta, c, m0, tid);
    __syncthreads();
    ds_pass<2>(0, U, b, c, m0, mt, tid, out);
    conv10v<4>(PB, PA, 0, H0Ac, H0Bc, 18, 37, 1281, ofs, tid);   // lv3 lowpass (PA dead)
    __syncthreads();
    u_pass<2, 2>(1, sRI, U, cw, roots, beta, c, m0, tid);
    __syncthreads();
    ds_pass<2>(1, U, b, c, m0, mt, tid, out);
    conv10v<4>(PB, sRI, 73, H1Ac, H1Bc, 18, 73, 73 + NBcnt, ofs, tid); // bp3
    __syncthreads();

    // ================= j = 3 (D=4), interleave bp4 =================
    u_pass<4, 3>(0, sRI, U, cw, roots, beta, c, m0, tid);
    __syncthreads();
    ds_pass<3>(0, U, b, c, m0, mt, tid, out);
    __syncthreads();
    u_pass<4, 3>(1, sRI, U, cw, roots, beta, c, m0, tid);
    __syncthreads();
    ds_pass<3>(1, U, b, c, m0, mt, tid, out);
    conv10v<8>(PA, sRI, 73, H1Ac, H1Bc, 36, 73, 73 + NBcnt, ofs, tid); // bp4
    __syncthreads();

    // ================= j = 4 (D=8) =================
    u_pass<8, 4>(0, sRI, U, cw, roots, beta, c, m0, tid);
    __syncthreads();
    ds_pass<4>(0, U, b, c, m0, mt, tid, out);
    __syncthreads();
    u_pass<8, 4>(1, sRI, U, cw, roots, beta, c, m0, tid);
    __syncthreads();
    ds_pass<4>(1, U, b, c, m0, mt, tid, out);
}

// ---------------- launch ----------------
extern "C" void kernel_launch(void* const* d_in, const int* in_sizes, int n_in,
                              void* d_out, int out_size, void* d_ws, size_t ws_size,
                              hipStream_t stream) {
    (void)in_sizes; (void)n_in; (void)out_size; (void)d_ws; (void)ws_size;
    const float* x     = (const float*)d_in[0];
    const float* cw    = (const float*)d_in[1];
    const float* roots = (const float*)d_in[2];
    const float* beta  = (const float*)d_in[3];
    float* out = (float*)d_out;

    dim3 grid(NOUT / M2, B_ * C_);       // (64, 16) = 1024 blocks
    murenn_all<<<grid, 256, 0, stream>>>(x, cw, roots, beta, out);
}

// Round 9
// 202.818 us; speedup vs baseline: 1.0565x; 1.0565x over previous
//
#include <hip/hip_runtime.h>

typedef float v2f __attribute__((ext_vector_type(2)));

// ---------------- problem constants ----------------
#define B_    4
#define C_    4
#define Q_    8
#define J_    5
#define T_    15
#define NSIG  65536
#define N2SIG 32768
#define NOUT  16384
#define NCH   16

// ---------------- wavelet filters ----------------
constexpr float H0Oc[13] = {
    -0.00455690456024f, -0.00543947593727f,  0.01702522388155f,  0.02382538479492f,
    -0.10671180468666f,  0.01186609203379f,  0.56881042071212f,  0.75614564389252f,
     0.27529538466888f, -0.11720388769911f, -0.03887280126882f,  0.03466034684485f,
    -0.00388321199915f };
constexpr float H1Oc[13] = {
    -0.00388321199915f, -0.03466034684485f, -0.03887280126882f,  0.11720388769911f,
     0.27529538466888f, -0.75614564389252f,  0.56881042071212f, -0.01186609203379f,
    -0.10671180468666f, -0.02382538479492f,  0.01702522388155f,  0.00543947593727f,
    -0.00455690456024f };
constexpr float H0Ac[10] = {
     0.03516384f, 0.0f, -0.08832942f, 0.23389032f, 0.76027237f,
     0.58751830f, 0.0f, -0.11430184f, 0.0f, 0.0f };
constexpr float H0Bc[10] = {
     0.0f, 0.0f, -0.11430184f, 0.0f, 0.58751830f,
     0.76027237f, 0.23389032f, -0.08832942f, 0.0f, 0.03516384f };
constexpr float H1Ac[10] = {
     0.0f, 0.0f, -0.11430184f, 0.0f, 0.58751830f,
    -0.76027237f, 0.23389032f, 0.08832942f, 0.0f, -0.03516384f };
constexpr float H1Bc[10] = {
    -0.03516384f, 0.0f, 0.08832942f, 0.23389032f, -0.76027237f,
     0.58751830f, 0.0f, -0.11430184f, 0.0f, 0.0f };

// fused two-stage lowpass+decimate: out[m] = sum_n g[n] * u[4m + n - 18]
struct Gtab { float v[37]; };
constexpr Gtab make_g() {
    Gtab g{};
    for (int n = 0; n < 37; ++n) {
        float s = 0.f;
        for (int k = 0; k < 13; ++k) {
            int l = n - 2 * k;
            if (l >= 0 && l < 13) s += H0Oc[k] * H0Oc[l];
        }
        g.v[n] = s;
    }
    return g;
}
constexpr Gtab cG = make_g();

__device__ __forceinline__ unsigned pack2bf(float a, float b) {
    unsigned ua = __float_as_uint(a) + 0x8000u;
    unsigned ub = __float_as_uint(b) + 0x8000u;
    return (ua >> 16) | (ub & 0xffff0000u);
}
__device__ __forceinline__ float unpk_lo(unsigned x) { return __uint_as_float(x << 16); }
__device__ __forceinline__ float unpk_hi(unsigned x) { return __uint_as_float(x & 0xffff0000u); }
__device__ __forceinline__ v2f zmask(v2f a, bool ok) {
    if (!ok) { a.x = 0.f; a.y = 0.f; }
    return a;
}

// ================= kernel 1: produce bp planes (bf16 R|I packed) =========
// grid (64, 16); tile = 1024 outputs, window 1184 (halo 80 each side)
#define T1   1024
#define S1   1184

__global__ __launch_bounds__(256) void udtcwt_produce(
        const float* __restrict__ x, unsigned* __restrict__ bp) {
    __shared__ __align__(16) float X[S1];
    __shared__ __align__(16) float L1[S1];
    __shared__ __align__(16) v2f PPa[S1];
    __shared__ __align__(16) v2f PPb[S1];
    const int tid = threadIdx.x;
    const int tile = blockIdx.x;
    const int ch   = blockIdx.y;
    const int gbase = tile * T1 - 80;
    const float* xc = x + (size_t)ch * NSIG;

    for (int p = tid; p < S1; p += 256) {
        int g = gbase + p;
        X[p] = ((unsigned)g < (unsigned)NSIG) ? xc[g] : 0.f;
    }
    __syncthreads();

    // bp0 (trees identical) + L1 lowpass
    for (int p = 80 + tid; p < 80 + T1; p += 256) {
        float a = 0.f;
        #pragma unroll
        for (int k = 0; k < 13; k++) a = fmaf(H1Oc[k], X[p + k - 6], a);
        bp[(size_t)(0 * NCH + ch) * NSIG + gbase + p] = pack2bf(a, a);
    }
    for (int p = 6 + tid; p < 1178; p += 256) {
        float a = 0.f;
        #pragma unroll
        for (int k = 0; k < 13; k++) a = fmaf(H0Oc[k], X[p + k - 6], a);
        L1[p] = ((unsigned)(gbase + p) < (unsigned)NSIG) ? a : 0.f;
    }
    __syncthreads();

    // bp1 + lv1 -> PPa (la2, lb2)
    for (int p = 80 + tid; p < 80 + T1; p += 256) {
        v2f r; r.x = 0.f; r.y = 0.f;
        #pragma unroll
        for (int k = 0; k < 10; k++) {
            v2f hk; hk.x = H1Ac[k]; hk.y = H1Bc[k];
            r += hk * L1[p + k - 4];
        }
        bp[(size_t)(1 * NCH + ch) * NSIG + gbase + p] = pack2bf(r.x, r.y);
    }
    for (int p = 10 + tid; p < 1174; p += 256) {
        v2f a; a.x = 0.f; a.y = 0.f;
        #pragma unroll
        for (int k = 0; k < 10; k++) {
            v2f hk; hk.x = H0Ac[k]; hk.y = H0Bc[k];
            a += hk * L1[p + k - 4];
        }
        PPa[p] = zmask(a, (unsigned)(gbase + p) < (unsigned)NSIG);
    }
    __syncthreads();

    // bp2 + lv2 (d=2) -> PPb (la3, lb3)
    for (int p = 80 + tid; p < 80 + T1; p += 256) {
        v2f r; r.x = 0.f; r.y = 0.f;
        #pragma unroll
        for (int k = 0; k < 10; k++) {
            v2f hk; hk.x = H1Ac[k]; hk.y = H1Bc[k];
            r += hk * PPa[p + 2 * k - 9];
        }
        bp[(size_t)(2 * NCH + ch) * NSIG + gbase + p] = pack2bf(r.x, r.y);
    }
    for (int p = 19 + tid; p < 1165; p += 256) {
        v2f a; a.x = 0.f; a.y = 0.f;
        #pragma unroll
        for (int k = 0; k < 10; k++) {
            v2f hk; hk.x = H0Ac[k]; hk.y = H0Bc[k];
            a += hk * PPa[p + 2 * k - 9];
        }
        PPb[p] = zmask(a, (unsigned)(gbase + p) < (unsigned)NSIG);
    }
    __syncthreads();

    // bp3 + lv3 (d=4) -> PPa (la4, lb4)  (old PPa dead)
    for (int p = 80 + tid; p < 80 + T1; p += 256) {
        v2f r; r.x = 0.f; r.y = 0.f;
        #pragma unroll
        for (int k = 0; k < 10; k++) {
            v2f hk; hk.x = H1Ac[k]; hk.y = H1Bc[k];
            r += hk * PPb[p + 4 * k - 18];
        }
        bp[(size_t)(3 * NCH + ch) * NSIG + gbase + p] = pack2bf(r.x, r.y);
    }
    for (int p = 37 + tid; p < 1147; p += 256) {
        v2f a; a.x = 0.f; a.y = 0.f;
        #pragma unroll
        for (int k = 0; k < 10; k++) {
            v2f hk; hk.x = H0Ac[k]; hk.y = H0Bc[k];
            a += hk * PPb[p + 4 * k - 18];
        }
        PPa[p] = zmask(a, (unsigned)(gbase + p) < (unsigned)NSIG);
    }
    __syncthreads();

    // bp4 (d=8)
    for (int p = 80 + tid; p < 80 + T1; p += 256) {
        v2f r; r.x = 0.f; r.y = 0.f;
        #pragma unroll
        for (int k = 0; k < 10; k++) {
            v2f hk; hk.x = H1Ac[k]; hk.y = H1Bc[k];
            r += hk * PPa[p + 8 * k - 36];
        }
        bp[(size_t)(4 * NCH + ch) * NSIG + gbase + p] = pack2bf(r.x, r.y);
    }
}

// ================= kernel 2: gconv + modulus + power + downsample =========
#define M2    256
#define NUcnt 1057               // 4*(M2-1) + 37
#define NBcnt 1169
// LDS: sRI v2f[1200] @0 | U uint2[1064] @2400 floats   -> 18112 B, 8 blocks/CU
#define SM2_FLOATS (2400 + 2128)

template<int D, int JJ>
__device__ __forceinline__ void u_pass(
        int g2, const v2f* __restrict__ sRI, uint2* __restrict__ U,
        const float* __restrict__ cw, const float* __restrict__ roots,
        float beta, int c, int m0, int tid) {
    const float lg_is = -0.5f * (float)JJ;
    const float beta2 = beta * exp2f(0.5f * (float)JJ);
    const int   u_lo  = 4 * m0 - 18;
    float w[4][T_], al[4], cq[4];
    #pragma unroll
    for (int qq = 0; qq < 4; ++qq) {
        const int o = c * Q_ + g2 * 4 + qq;
        #pragma unroll
        for (int t = 0; t < T_; t++) w[qq][t] = cw[(size_t)(JJ * 32 + o) * T_ + t];
        al[qq] = 1.f / (1.f + __expf(-roots[JJ * 32 + o]));
        cq[qq] = al[qq] * lg_is;
    }
    for (int i = tid; i < NUcnt; i += 256) {
        const int n = u_lo + i;
        const bool ok = ((unsigned)n < (unsigned)NSIG);
        const v2f* tp = sRI + (i + 56 - 7 * D);
        v2f tap[T_];
        #pragma unroll
        for (int t = 0; t < T_; t++) tap[t] = tp[t * D];
        float uq[4];
        #pragma unroll
        for (int qq = 0; qq < 4; ++qq) {
            v2f ri; ri.x = 0.f; ri.y = 0.f;
            #pragma unroll
            for (int t = 0; t < T_; t++) ri += w[qq][t] * tap[t];
            float z2 = fmaf(ri.x, ri.x, ri.y * ri.y);
            float us = sqrtf(z2);
            float lg = __log2f(us + beta2);
            float u  = exp2f(fmaf(al[qq], lg, cq[qq]));
            uq[qq] = ok ? u : 0.f;
        }
        uint2 p;
        p.x = pack2bf(uq[0], uq[1]);
        p.y = pack2bf(uq[2], uq[3]);
        U[i] = p;
    }
}

template<int JJ>
__device__ __forceinline__ void ds_pass(
        int g2, const uint2* __restrict__ U,
        int b, int c, int m0, int mt, int tid, float* __restrict__ out) {
    const int m = m0 + tid;
    const bool edge = (mt == 0 && tid < 3) || (mt == 63 && tid >= 253);
    float a0 = 0.f, a1 = 0.f, a2 = 0.f, a3 = 0.f;
    #pragma unroll
    for (int nn = 0; nn < 37; ++nn) {
        uint2 t = U[4 * tid + nn];
        a0 = fmaf(cG.v[nn], unpk_lo(t.x), a0);
        a1 = fmaf(cG.v[nn], unpk_hi(t.x), a1);
        a2 = fmaf(cG.v[nn], unpk_lo(t.y), a2);
        a3 = fmaf(cG.v[nn], unpk_hi(t.y), a3);
    }
    if (edge) {
        float e0 = 0.f, e1 = 0.f, e2 = 0.f, e3 = 0.f;
        for (int k = 0; k < 13; ++k) {
            int p = 2 * m + k - 6;
            if (p < 0 || p >= N2SIG) continue;
            float v0 = 0.f, v1 = 0.f, v2 = 0.f, v3 = 0.f;
            for (int l = 0; l < 13; ++l) {
                uint2 t = U[4 * tid + 2 * k + l];
                v0 = fmaf(H0Oc[l], unpk_lo(t.x), v0);
                v1 = fmaf(H0Oc[l], unpk_hi(t.x), v1);
                v2 = fmaf(H0Oc[l], unpk_lo(t.y), v2);
                v3 = fmaf(H0Oc[l], unpk_hi(t.y), v3);
            }
            e0 = fmaf(H0Oc[k], v0, e0); e1 = fmaf(H0Oc[k], v1, e1);
            e2 = fmaf(H0Oc[k], v2, e2); e3 = fmaf(H0Oc[k], v3, e3);
        }
        a0 = e0; a1 = e1; a2 = e2; a3 = e3;
    }
    const int o = c * Q_ + g2 * 4;
    float* ob = out + ((size_t)b * 160 + JJ * 32 + o) * NOUT + m;
    ob[0]        = a0;
    ob[NOUT]     = a1;
    ob[2 * NOUT] = a2;
    ob[3 * NOUT] = a3;
}

template<int D, int JJ>
__device__ __forceinline__ void post_all(
        const v2f* __restrict__ sRI, uint2* __restrict__ U,
        const float* __restrict__ cw, const float* __restrict__ roots,
        float beta, int b, int c, int m0, int mt, int tid, float* __restrict__ out) {
    #pragma unroll
    for (int g2 = 0; g2 < 2; ++g2) {
        u_pass<D, JJ>(g2, sRI, U, cw, roots, beta, c, m0, tid);
        __syncthreads();
        ds_pass<JJ>(g2, U, b, c, m0, mt, tid, out);
        __syncthreads();
    }
}

__global__ __launch_bounds__(256, 8) void murenn_post(
        const unsigned* __restrict__ bp,
        const float* __restrict__ cw,
        const float* __restrict__ roots,
        const float* __restrict__ beta_p,
        float* __restrict__ out) {
    __shared__ __align__(16) float smem[SM2_FLOATS];
    v2f*   sRI = (v2f*)smem;                 // 1200 v2f
    uint2* U   = (uint2*)(smem + 2400);      // 1064 uint2

    const int tid = threadIdx.x;
    const int mt  = blockIdx.x;              // 0..63
    const int ch  = blockIdx.y;              // b*C + c
    const int j   = blockIdx.z;              // 0..4
    const int b   = ch >> 2, c = ch & 3;
    const int m0  = mt * M2;
    const int bp_lo = 4 * m0 - 74;
    const float beta = beta_p[0];
    const unsigned* bpp = bp + (size_t)(j * NCH + ch) * NSIG;

    for (int i = tid; i < NBcnt; i += 256) {
        int n = bp_lo + i;
        unsigned pk = ((unsigned)n < (unsigned)NSIG) ? bpp[n] : 0u;
        v2f v; v.x = unpk_lo(pk); v.y = unpk_hi(pk);
        sRI[i] = v;
    }
    __syncthreads();

    if (j == 0)      post_all<1, 0>(sRI, U, cw, roots, beta, b, c, m0, mt, tid, out);
    else if (j == 1) post_all<1, 1>(sRI, U, cw, roots, beta, b, c, m0, mt, tid, out);
    else if (j == 2) post_all<2, 2>(sRI, U, cw, roots, beta, b, c, m0, mt, tid, out);
    else if (j == 3) post_all<4, 3>(sRI, U, cw, roots, beta, b, c, m0, mt, tid, out);
    else             post_all<8, 4>(sRI, U, cw, roots, beta, b, c, m0, mt, tid, out);
}

// ---------------- launch ----------------
extern "C" void kernel_launch(void* const* d_in, const int* in_sizes, int n_in,
                              void* d_out, int out_size, void* d_ws, size_t ws_size,
                              hipStream_t stream) {
    (void)in_sizes; (void)n_in; (void)out_size; (void)ws_size;
    const float* x     = (const float*)d_in[0];
    const float* cw    = (const float*)d_in[1];
    const float* roots = (const float*)d_in[2];
    const float* beta  = (const float*)d_in[3];
    float* out = (float*)d_out;
    unsigned* bp = (unsigned*)d_ws;          // 5*16*65536*4 B = 21 MB

    dim3 g1(NSIG / T1, NCH);                 // (64, 16)
    udtcwt_produce<<<g1, 256, 0, stream>>>(x, bp);

    dim3 g2(NOUT / M2, NCH, J_);             // (64, 16, 5) = 5120 blocks
    murenn_post<<<g2, 256, 0, stream>>>(bp, cw, roots, beta, out);
}

// Round 10
// 193.086 us; speedup vs baseline: 1.1097x; 1.0504x over previous
//
#include <hip/hip_runtime.h>

typedef float v2f __attribute__((ext_vector_type(2)));

// ---------------- problem constants ----------------
#define B_    4
#define C_    4
#define Q_    8
#define J_    5
#define T_    15
#define NSIG  65536
#define N2SIG 32768
#define NOUT  16384
#define NCH   16

// ---------------- wavelet filters ----------------
constexpr float H0Oc[13] = {
    -0.00455690456024f, -0.00543947593727f,  0.01702522388155f,  0.02382538479492f,
    -0.10671180468666f,  0.01186609203379f,  0.56881042071212f,  0.75614564389252f,
     0.27529538466888f, -0.11720388769911f, -0.03887280126882f,  0.03466034684485f,
    -0.00388321199915f };
constexpr float H1Oc[13] = {
    -0.00388321199915f, -0.03466034684485f, -0.03887280126882f,  0.11720388769911f,
     0.27529538466888f, -0.75614564389252f,  0.56881042071212f, -0.01186609203379f,
    -0.10671180468666f, -0.02382538479492f,  0.01702522388155f,  0.00543947593727f,
    -0.00455690456024f };
constexpr float H0Ac[10] = {
     0.03516384f, 0.0f, -0.08832942f, 0.23389032f, 0.76027237f,
     0.58751830f, 0.0f, -0.11430184f, 0.0f, 0.0f };
constexpr float H0Bc[10] = {
     0.0f, 0.0f, -0.11430184f, 0.0f, 0.58751830f,
     0.76027237f, 0.23389032f, -0.08832942f, 0.0f, 0.03516384f };
constexpr float H1Ac[10] = {
     0.0f, 0.0f, -0.11430184f, 0.0f, 0.58751830f,
    -0.76027237f, 0.23389032f, 0.08832942f, 0.0f, -0.03516384f };
constexpr float H1Bc[10] = {
    -0.03516384f, 0.0f, 0.08832942f, 0.23389032f, -0.76027237f,
     0.58751830f, 0.0f, -0.11430184f, 0.0f, 0.0f };

// fused two-stage lowpass+decimate: out[m] = sum_n g[n] * u[4m + n - 18]
struct Gtab { float v[37]; };
constexpr Gtab make_g() {
    Gtab g{};
    for (int n = 0; n < 37; ++n) {
        float s = 0.f;
        for (int k = 0; k < 13; ++k) {
            int l = n - 2 * k;
            if (l >= 0 && l < 13) s += H0Oc[k] * H0Oc[l];
        }
        g.v[n] = s;
    }
    return g;
}
constexpr Gtab cG = make_g();

__device__ __forceinline__ unsigned pack2bf(float a, float b) {
    unsigned ua = __float_as_uint(a) + 0x8000u;
    unsigned ub = __float_as_uint(b) + 0x8000u;
    return (ua >> 16) | (ub & 0xffff0000u);
}
__device__ __forceinline__ float unpk_lo(unsigned x) { return __uint_as_float(x << 16); }
__device__ __forceinline__ float unpk_hi(unsigned x) { return __uint_as_float(x & 0xffff0000u); }
__device__ __forceinline__ v2f zmask(v2f a, bool ok) {
    if (!ok) { a.x = 0.f; a.y = 0.f; }
    return a;
}

// ================= kernel 1: produce bp planes (bf16 R|I packed) =========
// grid (64, 16); tile = 1024 outputs, window 1184 (halo 80 each side)
#define T1   1024
#define S1   1184

__global__ __launch_bounds__(256) void udtcwt_produce(
        const float* __restrict__ x, unsigned* __restrict__ bp) {
    __shared__ __align__(16) float X[S1];
    __shared__ __align__(16) float L1[S1];
    __shared__ __align__(16) v2f PPa[S1];
    __shared__ __align__(16) v2f PPb[S1];
    const int tid = threadIdx.x;
    const int tile = blockIdx.x;
    const int ch   = blockIdx.y;
    const int gbase = tile * T1 - 80;
    const float* xc = x + (size_t)ch * NSIG;

    for (int p = tid; p < S1; p += 256) {
        int g = gbase + p;
        X[p] = ((unsigned)g < (unsigned)NSIG) ? xc[g] : 0.f;
    }
    __syncthreads();

    // bp0 (trees identical) + L1 lowpass
    for (int p = 80 + tid; p < 80 + T1; p += 256) {
        float a = 0.f;
        #pragma unroll
        for (int k = 0; k < 13; k++) a = fmaf(H1Oc[k], X[p + k - 6], a);
        bp[(size_t)(0 * NCH + ch) * NSIG + gbase + p] = pack2bf(a, a);
    }
    for (int p = 6 + tid; p < 1178; p += 256) {
        float a = 0.f;
        #pragma unroll
        for (int k = 0; k < 13; k++) a = fmaf(H0Oc[k], X[p + k - 6], a);
        L1[p] = ((unsigned)(gbase + p) < (unsigned)NSIG) ? a : 0.f;
    }
    __syncthreads();

    // bp1 + lv1 -> PPa (la2, lb2)
    for (int p = 80 + tid; p < 80 + T1; p += 256) {
        v2f r; r.x = 0.f; r.y = 0.f;
        #pragma unroll
        for (int k = 0; k < 10; k++) {
            v2f hk; hk.x = H1Ac[k]; hk.y = H1Bc[k];
            r += hk * L1[p + k - 4];
        }
        bp[(size_t)(1 * NCH + ch) * NSIG + gbase + p] = pack2bf(r.x, r.y);
    }
    for (int p = 10 + tid; p < 1174; p += 256) {
        v2f a; a.x = 0.f; a.y = 0.f;
        #pragma unroll
        for (int k = 0; k < 10; k++) {
            v2f hk; hk.x = H0Ac[k]; hk.y = H0Bc[k];
            a += hk * L1[p + k - 4];
        }
        PPa[p] = zmask(a, (unsigned)(gbase + p) < (unsigned)NSIG);
    }
    __syncthreads();

    // bp2 + lv2 (d=2) -> PPb (la3, lb3)
    for (int p = 80 + tid; p < 80 + T1; p += 256) {
        v2f r; r.x = 0.f; r.y = 0.f;
        #pragma unroll
        for (int k = 0; k < 10; k++) {
            v2f hk; hk.x = H1Ac[k]; hk.y = H1Bc[k];
            r += hk * PPa[p + 2 * k - 9];
        }
        bp[(size_t)(2 * NCH + ch) * NSIG + gbase + p] = pack2bf(r.x, r.y);
    }
    for (int p = 19 + tid; p < 1165; p += 256) {
        v2f a; a.x = 0.f; a.y = 0.f;
        #pragma unroll
        for (int k = 0; k < 10; k++) {
            v2f hk; hk.x = H0Ac[k]; hk.y = H0Bc[k];
            a += hk * PPa[p + 2 * k - 9];
        }
        PPb[p] = zmask(a, (unsigned)(gbase + p) < (unsigned)NSIG);
    }
    __syncthreads();

    // bp3 + lv3 (d=4) -> PPa (la4, lb4)  (old PPa dead)
    for (int p = 80 + tid; p < 80 + T1; p += 256) {
        v2f r; r.x = 0.f; r.y = 0.f;
        #pragma unroll
        for (int k = 0; k < 10; k++) {
            v2f hk; hk.x = H1Ac[k]; hk.y = H1Bc[k];
            r += hk * PPb[p + 4 * k - 18];
        }
        bp[(size_t)(3 * NCH + ch) * NSIG + gbase + p] = pack2bf(r.x, r.y);
    }
    for (int p = 37 + tid; p < 1147; p += 256) {
        v2f a; a.x = 0.f; a.y = 0.f;
        #pragma unroll
        for (int k = 0; k < 10; k++) {
            v2f hk; hk.x = H0Ac[k]; hk.y = H0Bc[k];
            a += hk * PPb[p + 4 * k - 18];
        }
        PPa[p] = zmask(a, (unsigned)(gbase + p) < (unsigned)NSIG);
    }
    __syncthreads();

    // bp4 (d=8)
    for (int p = 80 + tid; p < 80 + T1; p += 256) {
        v2f r; r.x = 0.f; r.y = 0.f;
        #pragma unroll
        for (int k = 0; k < 10; k++) {
            v2f hk; hk.x = H1Ac[k]; hk.y = H1Bc[k];
            r += hk * PPa[p + 8 * k - 36];
        }
        bp[(size_t)(4 * NCH + ch) * NSIG + gbase + p] = pack2bf(r.x, r.y);
    }
}

// ================= kernel 2: gconv + modulus + power + downsample =========
#define M2    256
#define NUcnt 1057               // 4*(M2-1) + 37
#define NBcnt 1169
// LDS: sRI v2f[1200] @0 | U uint2[1064] @2400 floats   -> 18112 B, 8 blocks/CU
#define SM2_FLOATS (2400 + 2128)

template<int D, int JJ>
__device__ __forceinline__ void u_pass(
        int g2, const v2f* __restrict__ sRI, uint2* __restrict__ U,
        const float* __restrict__ cw, const float* __restrict__ roots,
        float beta, int c, int m0, int tid) {
    const float lg_is = -0.5f * (float)JJ;
    const float beta2 = beta * exp2f(0.5f * (float)JJ);
    const int   u_lo  = 4 * m0 - 18;
    float w[4][T_], al[4], cq[4];
    #pragma unroll
    for (int qq = 0; qq < 4; ++qq) {
        const int o = c * Q_ + g2 * 4 + qq;
        #pragma unroll
        for (int t = 0; t < T_; t++) w[qq][t] = cw[(size_t)(JJ * 32 + o) * T_ + t];
        al[qq] = 1.f / (1.f + __expf(-roots[JJ * 32 + o]));
        cq[qq] = al[qq] * lg_is;
    }
    for (int i = tid; i < NUcnt; i += 256) {
        const int n = u_lo + i;
        const bool ok = ((unsigned)n < (unsigned)NSIG);
        const v2f* tp = sRI + (i + 56 - 7 * D);
        v2f tap[T_];
        #pragma unroll
        for (int t = 0; t < T_; t++) tap[t] = tp[t * D];
        float uq[4];
        #pragma unroll
        for (int qq = 0; qq < 4; ++qq) {
            v2f ri; ri.x = 0.f; ri.y = 0.f;
            #pragma unroll
            for (int t = 0; t < T_; t++) ri += w[qq][t] * tap[t];
            float z2 = fmaf(ri.x, ri.x, ri.y * ri.y);
            float us = sqrtf(z2);
            float lg = __log2f(us + beta2);
            float u  = exp2f(fmaf(al[qq], lg, cq[qq]));
            uq[qq] = ok ? u : 0.f;
        }
        uint2 p;
        p.x = pack2bf(uq[0], uq[1]);
        p.y = pack2bf(uq[2], uq[3]);
        U[i] = p;
    }
}

template<int JJ>
__device__ __forceinline__ void ds_pass(
        int g2, const uint2* __restrict__ U,
        int b, int c, int m0, int mt, int tid, float* __restrict__ out) {
    const int m = m0 + tid;
    const bool edge = (mt == 0 && tid < 3) || (mt == 63 && tid >= 253);
    float a0 = 0.f, a1 = 0.f, a2 = 0.f, a3 = 0.f;
    #pragma unroll
    for (int nn = 0; nn < 37; ++nn) {
        uint2 t = U[4 * tid + nn];
        a0 = fmaf(cG.v[nn], unpk_lo(t.x), a0);
        a1 = fmaf(cG.v[nn], unpk_hi(t.x), a1);
        a2 = fmaf(cG.v[nn], unpk_lo(t.y), a2);
        a3 = fmaf(cG.v[nn], unpk_hi(t.y), a3);
    }
    if (edge) {
        float e0 = 0.f, e1 = 0.f, e2 = 0.f, e3 = 0.f;
        for (int k = 0; k < 13; ++k) {
            int p = 2 * m + k - 6;
            if (p < 0 || p >= N2SIG) continue;
            float v0 = 0.f, v1 = 0.f, v2 = 0.f, v3 = 0.f;
            for (int l = 0; l < 13; ++l) {
                uint2 t = U[4 * tid + 2 * k + l];
                v0 = fmaf(H0Oc[l], unpk_lo(t.x), v0);
                v1 = fmaf(H0Oc[l], unpk_hi(t.x), v1);
                v2 = fmaf(H0Oc[l], unpk_lo(t.y), v2);
                v3 = fmaf(H0Oc[l], unpk_hi(t.y), v3);
            }
            e0 = fmaf(H0Oc[k], v0, e0); e1 = fmaf(H0Oc[k], v1, e1);
            e2 = fmaf(H0Oc[k], v2, e2); e3 = fmaf(H0Oc[k], v3, e3);
        }
        a0 = e0; a1 = e1; a2 = e2; a3 = e3;
    }
    const int o = c * Q_ + g2 * 4;
    float* ob = out + ((size_t)b * 160 + JJ * 32 + o) * NOUT + m;
    ob[0]        = a0;
    ob[NOUT]     = a1;
    ob[2 * NOUT] = a2;
    ob[3 * NOUT] = a3;
}

template<int D, int JJ>
__device__ __forceinline__ void post_all(
        const v2f* __restrict__ sRI, uint2* __restrict__ U,
        const float* __restrict__ cw, const float* __restrict__ roots,
        float beta, int b, int c, int m0, int mt, int tid, float* __restrict__ out) {
    #pragma unroll
    for (int g2 = 0; g2 < 2; ++g2) {
        u_pass<D, JJ>(g2, sRI, U, cw, roots, beta, c, m0, tid);
        __syncthreads();
        ds_pass<JJ>(g2, U, b, c, m0, mt, tid, out);
        __syncthreads();
    }
}

// (256,4): cap = 128 VGPR so tap[15] (30 VGPRs) + accumulators stay resident.
// Occupancy remains LDS-limited at 8 blocks/CU (18.1 KB), so no occupancy cost.
__global__ __launch_bounds__(256, 4) void murenn_post(
        const unsigned* __restrict__ bp,
        const float* __restrict__ cw,
        const float* __restrict__ roots,
        const float* __restrict__ beta_p,
        float* __restrict__ out) {
    __shared__ __align__(16) float smem[SM2_FLOATS];
    v2f*   sRI = (v2f*)smem;                 // 1200 v2f
    uint2* U   = (uint2*)(smem + 2400);      // 1064 uint2

    const int tid = threadIdx.x;
    const int mt  = blockIdx.x;              // 0..63
    const int ch  = blockIdx.y;              // b*C + c
    const int j   = blockIdx.z;              // 0..4
    const int b   = ch >> 2, c = ch & 3;
    const int m0  = mt * M2;
    const int bp_lo = 4 * m0 - 74;
    const float beta = beta_p[0];
    const unsigned* bpp = bp + (size_t)(j * NCH + ch) * NSIG;

    for (int i = tid; i < NBcnt; i += 256) {
        int n = bp_lo + i;
        unsigned pk = ((unsigned)n < (unsigned)NSIG) ? bpp[n] : 0u;
        v2f v; v.x = unpk_lo(pk); v.y = unpk_hi(pk);
        sRI[i] = v;
    }
    __syncthreads();

    if (j == 0)      post_all<1, 0>(sRI, U, cw, roots, beta, b, c, m0, mt, tid, out);
    else if (j == 1) post_all<1, 1>(sRI, U, cw, roots, beta, b, c, m0, mt, tid, out);
    else if (j == 2) post_all<2, 2>(sRI, U, cw, roots, beta, b, c, m0, mt, tid, out);
    else if (j == 3) post_all<4, 3>(sRI, U, cw, roots, beta, b, c, m0, mt, tid, out);
    else             post_all<8, 4>(sRI, U, cw, roots, beta, b, c, m0, mt, tid, out);
}

// ---------------- launch ----------------
extern "C" void kernel_launch(void* const* d_in, const int* in_sizes, int n_in,
                              void* d_out, int out_size, void* d_ws, size_t ws_size,
                              hipStream_t stream) {
    (void)in_sizes; (void)n_in; (void)out_size; (void)ws_size;
    const float* x     = (const float*)d_in[0];
    const float* cw    = (const float*)d_in[1];
    const float* roots = (const float*)d_in[2];
    const float* beta  = (const float*)d_in[3];
    float* out = (float*)d_out;
    unsigned* bp = (unsigned*)d_ws;          // 5*16*65536*4 B = 21 MB

    dim3 g1(NSIG / T1, NCH);                 // (64, 16)
    udtcwt_produce<<<g1, 256, 0, stream>>>(x, bp);

    dim3 g2(NOUT / M2, NCH, J_);             // (64, 16, 5) = 5120 blocks
    murenn_post<<<g2, 256, 0, stream>>>(bp, cw, roots, beta, out);
}